// Round 2
// baseline (850.500 us; speedup 1.0000x reference)
//
#include <hip/hip_runtime.h>

// Fused SpikingDenseLayer: B=256, T=100, F=K=1024, U=1024.
// One block = one (batch b, 128-wide u-tile). GEMM accumulates current[T][128]
// in registers (7 t-rows x 8 u-cols per thread, 16x16 thread grid), dumps to
// LDS, then a sequential LIF scan over T writes spikes + counts directly.
// Currents NEVER touch global memory -> no inter-kernel handoff, no
// dependence on d_out initial state.

#define UN 128              // u-columns per block
#define BK 16               // k-slice staged per iteration
#define TT 7                // t-rows per thread (16*7 = 112 >= T=100, padded rows are zero)
#define TU 8                // u-cols per thread
#define T_PAD 112
#define AS_STRIDE (T_PAD + 4)   // 116 floats
#define WS_STRIDE (UN + 4)      // 132 floats
#define CS_STRIDE (UN + 4)      // 132 floats
#define T_MAX 100

__global__ __launch_bounds__(256, 3) void fused_snn(
    const float* __restrict__ x,     // [B,T,F]
    const float* __restrict__ W,     // [F,U]
    const float* __restrict__ bias,  // [U]
    float* __restrict__ spikes,      // [B,T,U]
    float* __restrict__ counts,      // [B,U]
    int B, int T, int F, int U)
{
    // Union: staging tiles (As 16x116 + Ws 16x132 = 3968 floats) live at the
    // front; after the K-loop the whole region is reused as Cs[T][132].
    __shared__ float smem[T_MAX * CS_STRIDE];   // 52.8 KB -> 3 blocks/CU
    float* As = smem;                           // As[k][t]  (transposed A tile)
    float* Ws = smem + BK * AS_STRIDE;          // Ws[k][u]

    const int tid = threadIdx.x;
    const int ug  = tid >> 4;    // 0..15 -> u-group
    const int tg  = tid & 15;    // 0..15 -> t-group
    const int u0  = blockIdx.x * UN;
    const int b   = blockIdx.y;

    // One-time zero of padded A rows t in [T, T_PAD): staging never writes
    // them, so they stay zero for every K iteration.
    if (tid < BK * (T_PAD - T_MAX)) {           // 16 * 12 = 192
        const int k = tid / (T_PAD - T_MAX);
        const int t = T_MAX + tid % (T_PAD - T_MAX);
        As[k * AS_STRIDE + t] = 0.f;
    }

    float acc[TT][TU];
    #pragma unroll
    for (int i = 0; i < TT; i++)
        #pragma unroll
        for (int j = 0; j < TU; j++) acc[i][j] = 0.f;

    const float* xb = x + (size_t)b * T * F;

    // A staging: thread -> row at (and at+64), 4 k's
    const int at = tid >> 2;          // 0..63
    const int ac = (tid & 3) * 4;     // 0,4,8,12
    // W staging: thread -> k-row wk (and wk+8), 4 u's
    const int wk = tid >> 5;          // 0..7
    const int wu = (tid & 31) * 4;    // 0..124

    for (int k0 = 0; k0 < F; k0 += BK) {
        // ---- stage A (transposed: As[k][t]) ----
        {
            float4 v = *(const float4*)(xb + (size_t)at * F + k0 + ac);
            As[(ac + 0) * AS_STRIDE + at] = v.x;
            As[(ac + 1) * AS_STRIDE + at] = v.y;
            As[(ac + 2) * AS_STRIDE + at] = v.z;
            As[(ac + 3) * AS_STRIDE + at] = v.w;
            const int t2 = at + 64;
            if (t2 < T) {
                float4 w = *(const float4*)(xb + (size_t)t2 * F + k0 + ac);
                As[(ac + 0) * AS_STRIDE + t2] = w.x;
                As[(ac + 1) * AS_STRIDE + t2] = w.y;
                As[(ac + 2) * AS_STRIDE + t2] = w.z;
                As[(ac + 3) * AS_STRIDE + t2] = w.w;
            }
        }
        // ---- stage W ----
        #pragma unroll
        for (int r = 0; r < 2; r++) {
            const int kk = wk + r * 8;
            float4 v = *(const float4*)(W + (size_t)(k0 + kk) * U + u0 + wu);
            *(float4*)(&Ws[kk * WS_STRIDE + wu]) = v;
        }
        __syncthreads();

        // ---- compute: 7x8 micro-tile ----
        #pragma unroll
        for (int kk = 0; kk < BK; kk++) {
            float a[TT], bb[TU];
            #pragma unroll
            for (int i = 0; i < TT; i++)
                a[i] = As[kk * AS_STRIDE + tg * TT + i];
            float4 b0 = *(const float4*)(&Ws[kk * WS_STRIDE + ug * TU]);
            float4 b1 = *(const float4*)(&Ws[kk * WS_STRIDE + ug * TU + 4]);
            bb[0] = b0.x; bb[1] = b0.y; bb[2] = b0.z; bb[3] = b0.w;
            bb[4] = b1.x; bb[5] = b1.y; bb[6] = b1.z; bb[7] = b1.w;
            #pragma unroll
            for (int i = 0; i < TT; i++)
                #pragma unroll
                for (int j = 0; j < TU; j++)
                    acc[i][j] += a[i] * bb[j];
        }
        __syncthreads();   // also protects the Cs overwrite below on last iter
    }

    // ---- bias + dump currents to LDS (Cs reuses the whole smem region) ----
    float bb[TU];
    {
        float4 bv0 = *(const float4*)(bias + u0 + ug * TU);
        float4 bv1 = *(const float4*)(bias + u0 + ug * TU + 4);
        bb[0] = bv0.x; bb[1] = bv0.y; bb[2] = bv0.z; bb[3] = bv0.w;
        bb[4] = bv1.x; bb[5] = bv1.y; bb[6] = bv1.z; bb[7] = bv1.w;
    }
    #pragma unroll
    for (int i = 0; i < TT; i++) {
        const int t = tg * TT + i;
        if (t < T) {
            float4 c0, c1;
            c0.x = acc[i][0] + bb[0];
            c0.y = acc[i][1] + bb[1];
            c0.z = acc[i][2] + bb[2];
            c0.w = acc[i][3] + bb[3];
            c1.x = acc[i][4] + bb[4];
            c1.y = acc[i][5] + bb[5];
            c1.z = acc[i][6] + bb[6];
            c1.w = acc[i][7] + bb[7];
            *(float4*)(&smem[t * CS_STRIDE + ug * TU])     = c0;
            *(float4*)(&smem[t * CS_STRIDE + ug * TU + 4]) = c1;
        }
    }
    __syncthreads();

    // ---- LIF scan: one thread per u-column, sequential over t ----
    // fp contract OFF so rounding matches numpy elementwise exactly:
    // v = 0.25*v (exact) + round(0.75*c); spike = v > 1.0; v -= spike.
    if (tid < UN) {
#pragma clang fp contract(off)
        const int u = tid;
        float v = 0.f, cnt = 0.f;
        float* sp = spikes + (size_t)b * T * U + u0 + u;
        for (int t = 0; t < T; t++) {
            float c = smem[t * CS_STRIDE + u];
            v = 0.25f * v + 0.75f * c;
            float s = (v > 1.0f) ? 1.0f : 0.0f;
            v -= s;
            cnt += s;
            sp[(size_t)t * U] = s;
        }
        counts[(size_t)b * U + u0 + u] = cnt;
    }
}

extern "C" void kernel_launch(void* const* d_in, const int* in_sizes, int n_in,
                              void* d_out, int out_size, void* d_ws, size_t ws_size,
                              hipStream_t stream) {
    const float* x    = (const float*)d_in[0];  // [B,T,F]
    const float* kern = (const float*)d_in[1];  // [F,U]
    const float* bias = (const float*)d_in[2];  // [U]
    float* out = (float*)d_out;

    const int U = in_sizes[2];                 // 1024
    const int F = in_sizes[1] / U;             // 1024
    const int R = in_sizes[0] / F;             // B*T = 25600
    const int B = out_size / U - R;            // (R*U + B*U)/U - R = 256
    const int T = R / B;                       // 100

    float* spikes = out;
    float* counts = out + (size_t)R * U;

    dim3 grid(U / UN, B);                      // (8, 256)
    fused_snn<<<grid, 256, 0, stream>>>(x, kern, bias, spikes, counts,
                                        B, T, F, U);
}